// Round 10
// baseline (1554.493 us; speedup 1.0000x reference)
//
#include <hip/hip_runtime.h>
#include <hip/hip_bf16.h>

// GCN v20 — v18 base + SORT-FREE gather (bucket-LDS accumulate). 274.7 us ref.
//   r19 post-mortem: 16-node fused k_gm REFUTED (74 us): per-tile barrier +
//   4-node-granularity degree variance idled waves (occ 50%, hbm 2.3 TB/s,
//   8.5M bank conflicts). Dispatch bubbles also small (v16->v17 ~free).
//   v20 deletes the fine sort: k_csc scatters edges into 128-node buckets
//   (s4=(r<<7)|(c&127)); k_gather2 = 1 block/bucket, LDS f32-atomic
//   accumulate (lo/hi feature planes -> bank=j2, 2-way = free), dual-edge
//   256B/instr load pattern unchanged, then relu(dis*(acc+self))->bf16.
//   Work/block balanced +-2% (Poisson 2050 edges). Deletes k_fsort, rows4,
//   off; adds 1-block k_scan for bucket starts. k_mat separate (proven).

#define FDIM 64
#define NPART 4
#define GPB 64
#define NB 256
#define BW2 128
#define MAXP 1024
#define GPLIN 1024

typedef __hip_bfloat16 bf16;
typedef short v8s __attribute__((ext_vector_type(8)));
typedef float v4f __attribute__((ext_vector_type(4)));

static __device__ __forceinline__ float ulo2f(unsigned u) {
    union { unsigned x; float f; } v; v.x = u << 16; return v.f;
}
static __device__ __forceinline__ float uhi2f(unsigned u) {
    union { unsigned x; float f; } v; v.x = u & 0xFFFF0000u; return v.f;
}
static __device__ __forceinline__ unsigned f2bu(float f) {
    bf16 b = __float2bfloat16(f);
    return (unsigned)(*(unsigned short*)&b);
}

// --- dispatch 1: deg u8 partial hist (b < NPART*GPB) ∥ col bucket hist ---
__global__ __launch_bounds__(1024)
void k_h2(const int* __restrict__ row, const int* __restrict__ col,
          unsigned* __restrict__ part, int* __restrict__ M,
          int E, int n, int psize, int psize4, int P, int CH) {
    __shared__ unsigned sm[6256];
    int t = threadIdx.x, b = blockIdx.x;
    if (b < NPART * GPB) {
        int p = b >> 6, g = b & 63;
        int base = p * psize;
        int lim = n - base; if (lim > psize) lim = psize;
        int lim4 = (lim + 3) >> 2;
        for (int i = t; i < lim4; i += 1024) sm[i] = 0u;
        __syncthreads();
        // E % 4 == 0: every int4 batch is in-bounds and 16B-aligned.
        for (int e = (g * 1024 + t) * 4; e < E; e += GPB * 4096) {
            int4 r4 = *(const int4*)&row[e];
            int r0 = r4.x - base, r1 = r4.y - base, r2 = r4.z - base, r3 = r4.w - base;
            if ((unsigned)r0 < (unsigned)lim) atomicAdd(&sm[r0 >> 2], 1u << ((r0 & 3) * 8));
            if ((unsigned)r1 < (unsigned)lim) atomicAdd(&sm[r1 >> 2], 1u << ((r1 & 3) * 8));
            if ((unsigned)r2 < (unsigned)lim) atomicAdd(&sm[r2 >> 2], 1u << ((r2 & 3) * 8));
            if ((unsigned)r3 < (unsigned)lim) atomicAdd(&sm[r3 >> 2], 1u << ((r3 & 3) * 8));
        }
        __syncthreads();
        unsigned* dst = part + ((size_t)p * GPB + g) * psize4;
        for (int i = t; i < lim4; i += 1024) dst[i] = sm[i];
    } else {
        int cb = b - NPART * GPB;
        int* h = (int*)sm;
        for (int i = t; i < P; i += 1024) h[i] = 0;
        __syncthreads();
        int s = cb * CH, e = min(s + CH, E);   // multiples of 4 (CH % 4 == 0)
        for (int i = s + t * 4; i < e; i += 4096) {
            int4 c4 = *(const int4*)&col[i];
            atomicAdd(&h[c4.x >> 7], 1);
            atomicAdd(&h[c4.y >> 7], 1);
            atomicAdd(&h[c4.z >> 7], 1);
            atomicAdd(&h[c4.w >> 7], 1);
        }
        __syncthreads();
        for (int p = t; p < P; p += 1024) M[p * NB + cb] = h[p];
    }
}

// --- dis from u8 partials (4 nodes/thread) ∥ M scan pass 1 (per 256-tile) ---
__global__ void k_ds1(const unsigned* __restrict__ part, float* __restrict__ dis,
                      int* __restrict__ M, int* __restrict__ bsum,
                      int n, int psize4, int ndis4, int P) {
    __shared__ int sc[256];
    int t = threadIdx.x, b = blockIdx.x;
    if (b < ndis4) {
        int i4 = b * 256 + t;
        int i = i4 * 4;
        if (i >= n) return;
        int p = i4 / psize4, loc = i4 - p * psize4;
        const unsigned* src = part + (size_t)p * GPB * psize4 + loc;
        unsigned s0 = 0, s1 = 0, s2 = 0, s3 = 0;
        #pragma unroll 8
        for (int g = 0; g < GPB; ++g) {
            unsigned u = src[(size_t)g * psize4];
            s0 += u & 255u; s1 += (u >> 8) & 255u;
            s2 += (u >> 16) & 255u; s3 += u >> 24;
        }
        dis[i] = rsqrtf((float)s0 + 1.0f);
        if (i + 1 < n) dis[i + 1] = rsqrtf((float)s1 + 1.0f);
        if (i + 2 < n) dis[i + 2] = rsqrtf((float)s2 + 1.0f);
        if (i + 3 < n) dis[i + 3] = rsqrtf((float)s3 + 1.0f);
    } else {
        int sb = b - ndis4;          // sb == bucket id (tile == bucket row)
        int i = sb * 256 + t;
        int v = M[i];
        sc[t] = v;
        __syncthreads();
        for (int d = 1; d < 256; d <<= 1) {
            int u = (t >= d) ? sc[t - d] : 0;
            __syncthreads(); sc[t] += u; __syncthreads();
        }
        M[i] = sc[t] - v;
        if (t == 255) bsum[sb] = sc[255];
    }
}

// --- single-block exclusive scan of bsum[P] -> bs[P] (bucket starts) ---
__global__ __launch_bounds__(1024)
void k_scan(const int* __restrict__ bsum, int* __restrict__ bs, int P) {
    __shared__ int sc[1024];
    int t = threadIdx.x;
    int v = (t < P) ? bsum[t] : 0;
    sc[t] = v;
    __syncthreads();
    for (int d = 1; d < 1024; d <<= 1) {
        int u = (t >= d) ? sc[t - d] : 0;
        __syncthreads(); sc[t] += u; __syncthreads();
    }
    if (t < P) bs[t] = sc[t] - v;
}

// --- coarse scatter into 128-node buckets, 1024 threads, int4 sweep ---
__global__ __launch_bounds__(1024)
void k_csc(const int* __restrict__ row, const int* __restrict__ col,
           const int* __restrict__ M, const int* __restrict__ bs,
           int* __restrict__ s4, int E, int CH, int P) {
    __shared__ int cur[MAXP];
    int t = threadIdx.x, b = blockIdx.x;
    for (int p = t; p < P; p += 1024) cur[p] = bs[p] + M[p * NB + b];
    __syncthreads();
    int s = b * CH, e = min(s + CH, E);   // multiples of 4
    for (int i = s + t * 4; i < e; i += 4096) {
        int4 r4 = *(const int4*)&row[i];
        int4 c4 = *(const int4*)&col[i];
        int p0 = atomicAdd(&cur[c4.x >> 7], 1);
        s4[p0] = (r4.x << 7) | (c4.x & 127);
        int p1 = atomicAdd(&cur[c4.y >> 7], 1);
        s4[p1] = (r4.y << 7) | (c4.y & 127);
        int p2 = atomicAdd(&cur[c4.z >> 7], 1);
        s4[p2] = (r4.z << 7) | (c4.z & 127);
        int p3 = atomicAdd(&cur[c4.w >> 7], 1);
        s4[p3] = (r4.w << 7) | (c4.w & 127);
    }
}

// --- linear layer 1: g1 = bf16(dis * (concat(x,feat)@W1 + b1)) ---
__global__ __launch_bounds__(256, 4)
void k_linc(const float* __restrict__ x, const float* __restrict__ feat,
            const float* __restrict__ W, const float* __restrict__ bvec,
            const float* __restrict__ dis, bf16* __restrict__ g1, int n) {
    __shared__ float sIn[4][FDIM];
    int t = threadIdx.x;
    int local = t >> 6, j = t & 63;
    float Wreg[FDIM];
    #pragma unroll
    for (int k = 0; k < FDIM; ++k) Wreg[k] = W[k * FDIM + j];
    float bj = bvec[j];
    int gw = blockIdx.x * 4 + local;
    int nwl = GPLIN * 4;
    for (int w = gw; w < n; w += nwl) {
        sIn[local][j] = (j < 32) ? x[(size_t)w * 32 + j]
                                 : feat[(size_t)w * 32 + (j - 32)];
        __threadfence_block();
        float o = bj;
        #pragma unroll
        for (int k4 = 0; k4 < 16; ++k4) {
            float4 h4 = *(const float4*)&sIn[local][k4 * 4];
            o = fmaf(h4.x, Wreg[4 * k4 + 0], o);
            o = fmaf(h4.y, Wreg[4 * k4 + 1], o);
            o = fmaf(h4.z, Wreg[4 * k4 + 2], o);
            o = fmaf(h4.w, Wreg[4 * k4 + 3], o);
        }
        g1[(size_t)w * FDIM + j] = __float2bfloat16(dis[w] * o);
        __threadfence_block();
    }
}

// --- sort-free bucket gather: 1 block = 1 bucket of 128 target nodes.
// LDS f32 accumulate, lo/hi feature planes: accLo[c7][j2]=feat 2*j2,
// accHi=feat 2*j2+1 -> LDS-atomic bank = j2 (2-way alias, free).
// Edge loads keep the proven dual-edge form: half-wave h carries edge
// parity, ushort2/lane = 256 B (2 rows) per instr, 8-deep unroll.
// Finalize: a[w][j] = relu(dis[w]*(acc+g[w][j])) bf16.
__global__ __launch_bounds__(512, 4)
void k_gather2(const int* __restrict__ s4, const int* __restrict__ bs,
               const int* __restrict__ bsum, const float* __restrict__ dis,
               const bf16* __restrict__ g, bf16* __restrict__ a, int n) {
    __shared__ float accLo[BW2][32];
    __shared__ float accHi[BW2][32];
    int t = threadIdx.x, b = blockIdx.x;
    int wv = t >> 6, lane = t & 63;
    int h = lane >> 5, j2 = lane & 31;
    for (int i = t; i < BW2 * 32; i += 512) {
        ((float*)accLo)[i] = 0.0f;
        ((float*)accHi)[i] = 0.0f;
    }
    __syncthreads();
    const unsigned* g32 = (const unsigned*)g;
    int gs = bs[b], cnt = bsum[b];
    int ge = gs + cnt;
    int npairs = (cnt + 1) >> 1;
    for (int q = wv; q < npairs; q += 64) {
        #pragma unroll
        for (int u = 0; u < 8; ++u) {
            int qq = q + u * 8;
            int idx = gs + 2 * qq + h;
            int sv = s4[min(idx, ge - 1)];
            float wg = (idx < ge) ? 1.0f : 0.0f;
            int r = sv >> 7, c7 = sv & 127;
            unsigned uu = g32[(size_t)r * 32 + j2];
            atomicAdd(&accLo[c7][j2], wg * ulo2f(uu));
            atomicAdd(&accHi[c7][j2], wg * uhi2f(uu));
        }
    }
    __syncthreads();
    int w0 = b << 7;
    for (int i = t; i < BW2 * 32; i += 512) {
        int node = w0 + (i >> 5);
        if (node >= n) break;
        int jj = i & 31;
        unsigned su = g32[(size_t)node * 32 + jj];   // self loop
        float dv = dis[node];
        float v0 = fmaxf(dv * (accLo[i >> 5][jj] + ulo2f(su)), 0.0f);
        float v1 = fmaxf(dv * (accHi[i >> 5][jj] + uhi2f(su)), 0.0f);
        ((unsigned*)a)[(size_t)node * 32 + jj] = f2bu(v0) | (f2bu(v1) << 16);
    }
}

// --- MFMA matvec: o = A@W + b ; FINAL ? relu(o) f32 : bf16(dis*o) ---
// Layouts (guide-verified): A-frag A[m=lane&15][k=quad*8+j];
// B-frag B[k=quad*8+j][n=lane&15]; C/D: n=lane&15, m=quad*4+reg.
template <bool FINAL>
__global__ __launch_bounds__(256, 4)
void k_mat(const bf16* __restrict__ A, const float* __restrict__ W,
           const float* __restrict__ bvec, const float* __restrict__ dis,
           void* __restrict__ outp, int n) {
    __shared__ __align__(16) bf16 sWt[FDIM * FDIM];   // Wt[n][k] (transposed)
    int t = threadIdx.x;
    for (int idx = t; idx < FDIM * FDIM; idx += 256) {
        int kk = idx >> 6, nn = idx & 63;
        sWt[nn * FDIM + kk] = __float2bfloat16(W[idx]);
    }
    __syncthreads();
    int wave = t >> 6, lane = t & 63;
    int quad = lane >> 4, l15 = lane & 15;
    v8s bfr[4][2];
    #pragma unroll
    for (int nt = 0; nt < 4; ++nt) {
        #pragma unroll
        for (int kf = 0; kf < 2; ++kf)
            bfr[nt][kf] = *(const v8s*)&sWt[(nt * 16 + l15) * FDIM + kf * 32 + quad * 8];
    }
    float bj[4];
    #pragma unroll
    for (int nt = 0; nt < 4; ++nt) bj[nt] = bvec[nt * 16 + l15];

    int ntiles = (n + 15) >> 4;
    int step = gridDim.x * 4;
    for (int tile = blockIdx.x * 4 + wave; tile < ntiles; tile += step) {
        int m0 = tile << 4;
        int mA = m0 + l15; if (mA >= n) mA = n - 1;
        v8s af0 = *(const v8s*)&A[(size_t)mA * FDIM + quad * 8];
        v8s af1 = *(const v8s*)&A[(size_t)mA * FDIM + 32 + quad * 8];
        v4f acc[4];
        #pragma unroll
        for (int nt = 0; nt < 4; ++nt) {
            acc[nt] = (v4f){0.f, 0.f, 0.f, 0.f};
            acc[nt] = __builtin_amdgcn_mfma_f32_16x16x32_bf16(af0, bfr[nt][0], acc[nt], 0, 0, 0);
            acc[nt] = __builtin_amdgcn_mfma_f32_16x16x32_bf16(af1, bfr[nt][1], acc[nt], 0, 0, 0);
        }
        #pragma unroll
        for (int r = 0; r < 4; ++r) {
            int node = m0 + quad * 4 + r;
            if (node >= n) continue;
            float dv = FINAL ? 0.0f : dis[node];
            #pragma unroll
            for (int nt = 0; nt < 4; ++nt) {
                int j = nt * 16 + l15;
                float o = acc[nt][r] + bj[nt];
                if (FINAL) ((float*)outp)[(size_t)node * FDIM + j] = fmaxf(o, 0.0f);
                else ((bf16*)outp)[(size_t)node * FDIM + j] = __float2bfloat16(dv * o);
            }
        }
    }
}

extern "C" void kernel_launch(void* const* d_in, const int* in_sizes, int n_in,
                              void* d_out, int out_size, void* d_ws, size_t ws_size,
                              hipStream_t stream) {
    const float* x    = (const float*)d_in[0];
    const float* feat = (const float*)d_in[1];
    const int*   ei   = (const int*)d_in[2];
    const float* W1   = (const float*)d_in[3];
    const float* b1   = (const float*)d_in[4];
    const float* W2   = (const float*)d_in[5];
    const float* b2   = (const float*)d_in[6];
    const float* Wfc  = (const float*)d_in[7];
    const float* bfc  = (const float*)d_in[8];
    float* out = (float*)d_out;

    const int n = in_sizes[0] / 32;   // 100000
    const int E = in_sizes[2] / 2;    // 1600000 (multiple of 4)
    const int* row = ei;
    const int* col = ei + E;

    const int psize = (((n + NPART - 1) / NPART) + 3) & ~3;   // 25000
    const int psize4 = psize >> 2;                            // 6250
    const int P  = (n + BW2 - 1) / BW2;                       // 782 buckets
    const int CH = (((E + NB - 1) / NB) + 3) & ~3;            // 6252 (x4 aligned)
    const int total = P * NB;                                 // 200192
    const int ndis4 = (((n + 3) / 4) + 255) / 256;            // 98

    // ws: dis[n] | M[total] | bsum[1024] | bs[1024] | s4[E]
    //     | (16B-aligned) bufA(bf16 64n) | bufB(bf16 64n)
    // part (NPART*GPB*psize4 u32 = 6.4 MB) aliases bufA (consumed in k_ds1
    // before k_linc writes g1 into bufA).
    float* dis  = (float*)d_ws;
    int*   M    = (int*)(dis + n);
    int*   bsum = M + (size_t)total;
    int*   bs   = bsum + 1024;
    int*   s4   = bs + 1024;
    size_t co = (size_t)(s4 + E - (int*)d_ws);
    co = (co + 3) & ~(size_t)3;                  // 16B align for v8s loads
    bf16*  bufA  = (bf16*)((int*)d_ws + co);
    bf16*  bufB  = bufA + (size_t)n * FDIM;
    unsigned* part = (unsigned*)bufA;

    k_h2<<<NPART * GPB + NB, 1024, 0, stream>>>(row, col, part, M, E, n,
                                                psize, psize4, P, CH);
    k_ds1<<<ndis4 + P, 256, 0, stream>>>(part, dis, M, bsum, n, psize4, ndis4, P);
    k_scan<<<1, 1024, 0, stream>>>(bsum, bs, P);
    k_csc<<<NB, 1024, 0, stream>>>(row, col, M, bs, s4, E, CH, P);
    k_linc<<<GPLIN, 256, 0, stream>>>(x, feat, W1, b1, dis, bufA, n);
    // layer 2: a1 = relu-gather(g1) ; g2 = bf16(dis*(a1@W2+b2))
    k_gather2<<<P, 512, 0, stream>>>(s4, bs, bsum, dis, bufA, bufB, n);
    k_mat<false><<<512, 256, 0, stream>>>(bufB, W2, b2, dis, bufA, n);
    // fc: a2 = relu-gather(g2) ; out = relu(a2@Wfc+bfc)
    k_gather2<<<P, 512, 0, stream>>>(s4, bs, bsum, dis, bufA, bufB, n);
    k_mat<true><<<512, 256, 0, stream>>>(bufB, Wfc, bfc, dis, out, n);
}

// Round 11
// 271.960 us; speedup vs baseline: 5.7159x; 5.7159x over previous
//
#include <hip/hip_runtime.h>
#include <hip/hip_bf16.h>

// GCN v21 — v18 revert (proven 274.7 us) + single delta: k_hd∥k_hc merged.
//   r20 post-mortem: bucket-LDS gather REFUTED hard (702 us): 6.2K waves
//   (vs 100K) x serialized MLP (VGPR=12 forced 1 load in flight) = ~100x
//   short of Little's-law line count. r19: fine-grain fusion REFUTED
//   (barrier + degree variance). The v14-form gather (100K waves, 8-deep
//   unroll, dual-edge 256B/instr) is the proven local optimum.
//   v21 = v18 byte-identical except k_h2 merges the two independent
//   histogram sweeps (deg u8 partials ∥ col coarse hist) into one
//   512-block dispatch (merge pattern ran correctly in v19): 10 -> 9
//   dispatches, one ramp/drain tail removed.

#define FDIM 64
#define NPART 4
#define GPB 64
#define NB 256
#define BW 512
#define MAXP 1024
#define GPLIN 1024

typedef __hip_bfloat16 bf16;
typedef short v8s __attribute__((ext_vector_type(8)));
typedef float v4f __attribute__((ext_vector_type(4)));

static __device__ __forceinline__ float ulo2f(unsigned u) {
    union { unsigned x; float f; } v; v.x = u << 16; return v.f;
}
static __device__ __forceinline__ float uhi2f(unsigned u) {
    union { unsigned x; float f; } v; v.x = u & 0xFFFF0000u; return v.f;
}
static __device__ __forceinline__ unsigned f2bu(float f) {
    bf16 b = __float2bfloat16(f);
    return (unsigned)(*(unsigned short*)&b);
}

// --- dispatch 1: deg u8 partial hist (b < NPART*GPB) ∥ col coarse hist ---
__global__ __launch_bounds__(1024)
void k_h2(const int* __restrict__ row, const int* __restrict__ col,
          unsigned* __restrict__ part, int* __restrict__ M,
          int E, int n, int psize, int psize4, int P, int CH) {
    __shared__ unsigned sm[6256];
    int t = threadIdx.x, b = blockIdx.x;
    if (b < NPART * GPB) {
        int p = b >> 6, g = b & 63;
        int base = p * psize;
        int lim = n - base; if (lim > psize) lim = psize;
        int lim4 = (lim + 3) >> 2;
        for (int i = t; i < lim4; i += 1024) sm[i] = 0u;
        __syncthreads();
        // E % 4 == 0: every int4 batch is in-bounds and 16B-aligned.
        for (int e = (g * 1024 + t) * 4; e < E; e += GPB * 4096) {
            int4 r4 = *(const int4*)&row[e];
            int r0 = r4.x - base, r1 = r4.y - base, r2 = r4.z - base, r3 = r4.w - base;
            if ((unsigned)r0 < (unsigned)lim) atomicAdd(&sm[r0 >> 2], 1u << ((r0 & 3) * 8));
            if ((unsigned)r1 < (unsigned)lim) atomicAdd(&sm[r1 >> 2], 1u << ((r1 & 3) * 8));
            if ((unsigned)r2 < (unsigned)lim) atomicAdd(&sm[r2 >> 2], 1u << ((r2 & 3) * 8));
            if ((unsigned)r3 < (unsigned)lim) atomicAdd(&sm[r3 >> 2], 1u << ((r3 & 3) * 8));
        }
        __syncthreads();
        unsigned* dst = part + ((size_t)p * GPB + g) * psize4;
        for (int i = t; i < lim4; i += 1024) dst[i] = sm[i];
    } else {
        int cb = b - NPART * GPB;
        int* h = (int*)sm;
        for (int i = t; i < P; i += 1024) h[i] = 0;
        __syncthreads();
        int s = cb * CH, e = min(s + CH, E);   // multiples of 4 (CH % 4 == 0)
        for (int i = s + t * 4; i < e; i += 4096) {
            int4 c4 = *(const int4*)&col[i];
            atomicAdd(&h[c4.x >> 9], 1);
            atomicAdd(&h[c4.y >> 9], 1);
            atomicAdd(&h[c4.z >> 9], 1);
            atomicAdd(&h[c4.w >> 9], 1);
        }
        __syncthreads();
        for (int p = t; p < P; p += 1024) M[p * NB + cb] = h[p];
    }
}

// --- dis from u8 partials (4 nodes/thread) ∥ scan pass 1 ---
__global__ void k_ds1(const unsigned* __restrict__ part, float* __restrict__ dis,
                      int* __restrict__ M, int* __restrict__ bsum,
                      int n, int psize4, int ndis4, int P) {
    __shared__ int sc[256];
    int t = threadIdx.x, b = blockIdx.x;
    if (b < ndis4) {
        int i4 = b * 256 + t;
        int i = i4 * 4;
        if (i >= n) return;
        int p = i4 / psize4, loc = i4 - p * psize4;
        const unsigned* src = part + (size_t)p * GPB * psize4 + loc;
        unsigned s0 = 0, s1 = 0, s2 = 0, s3 = 0;
        #pragma unroll 8
        for (int g = 0; g < GPB; ++g) {
            unsigned u = src[(size_t)g * psize4];
            s0 += u & 255u; s1 += (u >> 8) & 255u;
            s2 += (u >> 16) & 255u; s3 += u >> 24;
        }
        dis[i] = rsqrtf((float)s0 + 1.0f);
        if (i + 1 < n) dis[i + 1] = rsqrtf((float)s1 + 1.0f);
        if (i + 2 < n) dis[i + 2] = rsqrtf((float)s2 + 1.0f);
        if (i + 3 < n) dis[i + 3] = rsqrtf((float)s3 + 1.0f);
    } else {
        int sb = b - ndis4;
        int i = sb * 256 + t;
        int v = M[i];
        sc[t] = v;
        __syncthreads();
        for (int d = 1; d < 256; d <<= 1) {
            int u = (t >= d) ? sc[t - d] : 0;
            __syncthreads(); sc[t] += u; __syncthreads();
        }
        M[i] = sc[t] - v;
        if (t == 255) bsum[sb] = sc[255];
    }
}

// --- coarse scatter, 1024 threads, int4 sweep (scan guarded to t<256) ---
__global__ __launch_bounds__(1024)
void k_csc(const int* __restrict__ row, const int* __restrict__ col,
           const int* __restrict__ M, const int* __restrict__ bsum,
           int* __restrict__ s4, int E, int CH, int P) {
    __shared__ int sc[256];
    __shared__ int bs[256];
    __shared__ int cur[MAXP];
    int t = threadIdx.x, b = blockIdx.x;
    if (t < 256) { int v = (t < P) ? bsum[t] : 0; sc[t] = v; bs[t] = v; }
    __syncthreads();
    for (int d = 1; d < 256; d <<= 1) {
        int u = (t < 256 && t >= d) ? sc[t - d] : 0;
        __syncthreads();
        if (t < 256) sc[t] += u;
        __syncthreads();
    }
    if (t < 256) bs[t] = sc[t] - bs[t];
    __syncthreads();
    for (int p = t; p < P; p += 1024) cur[p] = bs[p] + M[p * NB + b];
    __syncthreads();
    int s = b * CH, e = min(s + CH, E);   // multiples of 4
    for (int i = s + t * 4; i < e; i += 4096) {
        int4 r4 = *(const int4*)&row[i];
        int4 c4 = *(const int4*)&col[i];
        int p0 = atomicAdd(&cur[c4.x >> 9], 1);
        s4[p0] = (r4.x << 9) | (c4.x & 511);
        int p1 = atomicAdd(&cur[c4.y >> 9], 1);
        s4[p1] = (r4.y << 9) | (c4.y & 511);
        int p2 = atomicAdd(&cur[c4.z >> 9], 1);
        s4[p2] = (r4.z << 9) | (c4.z & 511);
        int p3 = atomicAdd(&cur[c4.w >> 9], 1);
        s4[p3] = (r4.w << 9) | (c4.w & 511);
    }
}

// --- fine counting sort, 1024 threads (scans guarded to t<256) ---
__global__ __launch_bounds__(1024)
void k_fsort(const int* __restrict__ s4, const int* __restrict__ bsum,
             int* __restrict__ rows4, int* __restrict__ off,
             int n, int E, int P) {
    __shared__ int sc[256];
    __shared__ int bs[256];
    __shared__ int hist[BW];
    __shared__ int loff[BW];
    __shared__ int tmp[256];
    int t = threadIdx.x, b = blockIdx.x;
    if (t < 256) { int v = (t < P) ? bsum[t] : 0; sc[t] = v; bs[t] = v; }
    __syncthreads();
    for (int d = 1; d < 256; d <<= 1) {
        int u = (t < 256 && t >= d) ? sc[t - d] : 0;
        __syncthreads();
        if (t < 256) sc[t] += u;
        __syncthreads();
    }
    if (t < 256) bs[t] = sc[t] - bs[t];
    __syncthreads();
    int gs = bs[b];
    int ge = gs + bsum[b];
    int c0 = b << 9;
    int lim = n - c0; if (lim > BW) lim = BW;
    for (int i = t; i < BW; i += 1024) hist[i] = 0;
    __syncthreads();
    for (int i = gs + t; i < ge; i += 1024)
        atomicAdd(&hist[s4[i] & 511], 1);
    __syncthreads();
    int s0 = 0, s1v = 0, ps = 0;
    if (t < 256) {
        s0 = hist[2 * t]; s1v = hist[2 * t + 1];
        ps = s0 + s1v;
        tmp[t] = ps;
    }
    __syncthreads();
    for (int d = 1; d < 256; d <<= 1) {
        int u = (t < 256 && t >= d) ? tmp[t - d] : 0;
        __syncthreads();
        if (t < 256) tmp[t] += u;
        __syncthreads();
    }
    if (t < 256) {
        int ex = tmp[t] - ps;
        loff[2 * t] = ex;
        loff[2 * t + 1] = ex + s0;
    }
    __syncthreads();
    for (int i = t; i < lim; i += 1024) off[c0 + i] = gs + loff[i];
    if (b == P - 1 && t == 0) off[n] = E;
    __syncthreads();
    for (int i = gs + t; i < ge; i += 1024) {
        int v2 = s4[i];
        int pos = gs + atomicAdd(&loff[v2 & 511], 1);
        rows4[pos] = v2 >> 9;
    }
}

// --- linear layer 1: g1 = bf16(dis * (concat(x,feat)@W1 + b1)) ---
__global__ __launch_bounds__(256, 4)
void k_linc(const float* __restrict__ x, const float* __restrict__ feat,
            const float* __restrict__ W, const float* __restrict__ bvec,
            const float* __restrict__ dis, bf16* __restrict__ g1, int n) {
    __shared__ float sIn[4][FDIM];
    int t = threadIdx.x;
    int local = t >> 6, j = t & 63;
    float Wreg[FDIM];
    #pragma unroll
    for (int k = 0; k < FDIM; ++k) Wreg[k] = W[k * FDIM + j];
    float bj = bvec[j];
    int gw = blockIdx.x * 4 + local;
    int nwl = GPLIN * 4;
    for (int w = gw; w < n; w += nwl) {
        sIn[local][j] = (j < 32) ? x[(size_t)w * 32 + j]
                                 : feat[(size_t)w * 32 + (j - 32)];
        __threadfence_block();
        float o = bj;
        #pragma unroll
        for (int k4 = 0; k4 < 16; ++k4) {
            float4 h4 = *(const float4*)&sIn[local][k4 * 4];
            o = fmaf(h4.x, Wreg[4 * k4 + 0], o);
            o = fmaf(h4.y, Wreg[4 * k4 + 1], o);
            o = fmaf(h4.z, Wreg[4 * k4 + 2], o);
            o = fmaf(h4.w, Wreg[4 * k4 + 3], o);
        }
        g1[(size_t)w * FDIM + j] = __float2bfloat16(dis[w] * o);
        __threadfence_block();
    }
}

// --- dual-edge gather + tail-split (proven 50.3-50.6 us): a[w][j] =
// relu(dis[w]*(g[w][j]+Σ g[r][j])). Wave = 1 node; half-wave h carries
// edge-slot parity, ushort2 per lane = 256 B (2 rows) per instruction;
// 8-deep unroll keeps 8 loads in flight. Full chunks clamp-free.
__global__ __launch_bounds__(256, 8)
void k_gather(const int* __restrict__ rows4, const int* __restrict__ off,
              const float* __restrict__ dis, const bf16* __restrict__ g,
              bf16* __restrict__ a, int n) {
    int t = blockIdx.x * blockDim.x + threadIdx.x;
    int w = t >> 6;
    if (w >= n) return;
    int lane = threadIdx.x & 63;
    int h = lane >> 5;          // edge-slot parity
    int j2 = lane & 31;         // feature pair index
    const unsigned* g32 = (const unsigned*)g;   // one row = 32 uints
    float acc0 = 0.0f, acc1 = 0.0f;
    int s = off[w], e = off[w + 1];
    int k = s;
    for (; k + 16 <= e; k += 16) {
        #pragma unroll
        for (int i = 0; i < 8; ++i) {
            int r = rows4[k + 2 * i + h];
            unsigned u = g32[(size_t)r * 32 + j2];
            acc0 += ulo2f(u);
            acc1 += uhi2f(u);
        }
    }
    if (k < e) {
        #pragma unroll
        for (int i = 0; i < 8; ++i) {
            int idx = k + 2 * i + h;
            int r = rows4[min(idx, e - 1)];
            unsigned u = g32[(size_t)r * 32 + j2];
            float wg = (idx < e) ? 1.0f : 0.0f;
            acc0 = fmaf(wg, ulo2f(u), acc0);
            acc1 = fmaf(wg, uhi2f(u), acc1);
        }
    }
    acc0 += __shfl_xor(acc0, 32, 64);
    acc1 += __shfl_xor(acc1, 32, 64);
    if (h == 0) {
        unsigned su = g32[(size_t)w * 32 + j2];    // self loop
        float dv = dis[w];
        float v0 = fmaxf(dv * (acc0 + ulo2f(su)), 0.0f);
        float v1 = fmaxf(dv * (acc1 + uhi2f(su)), 0.0f);
        ((unsigned*)a)[(size_t)w * 32 + j2] = f2bu(v0) | (f2bu(v1) << 16);
    }
}

// --- MFMA matvec: o = A@W + b ; FINAL ? relu(o) f32 : bf16(dis*o) ---
// Layouts (guide-verified): A-frag A[m=lane&15][k=quad*8+j];
// B-frag B[k=quad*8+j][n=lane&15]; C/D: n=lane&15, m=quad*4+reg.
template <bool FINAL>
__global__ __launch_bounds__(256, 4)
void k_mat(const bf16* __restrict__ A, const float* __restrict__ W,
           const float* __restrict__ bvec, const float* __restrict__ dis,
           void* __restrict__ outp, int n) {
    __shared__ __align__(16) bf16 sWt[FDIM * FDIM];   // Wt[n][k] (transposed)
    int t = threadIdx.x;
    for (int idx = t; idx < FDIM * FDIM; idx += 256) {
        int kk = idx >> 6, nn = idx & 63;
        sWt[nn * FDIM + kk] = __float2bfloat16(W[idx]);
    }
    __syncthreads();
    int wave = t >> 6, lane = t & 63;
    int quad = lane >> 4, l15 = lane & 15;
    v8s bfr[4][2];
    #pragma unroll
    for (int nt = 0; nt < 4; ++nt) {
        #pragma unroll
        for (int kf = 0; kf < 2; ++kf)
            bfr[nt][kf] = *(const v8s*)&sWt[(nt * 16 + l15) * FDIM + kf * 32 + quad * 8];
    }
    float bj[4];
    #pragma unroll
    for (int nt = 0; nt < 4; ++nt) bj[nt] = bvec[nt * 16 + l15];

    int ntiles = (n + 15) >> 4;
    int step = gridDim.x * 4;
    for (int tile = blockIdx.x * 4 + wave; tile < ntiles; tile += step) {
        int m0 = tile << 4;
        int mA = m0 + l15; if (mA >= n) mA = n - 1;
        v8s af0 = *(const v8s*)&A[(size_t)mA * FDIM + quad * 8];
        v8s af1 = *(const v8s*)&A[(size_t)mA * FDIM + 32 + quad * 8];
        v4f acc[4];
        #pragma unroll
        for (int nt = 0; nt < 4; ++nt) {
            acc[nt] = (v4f){0.f, 0.f, 0.f, 0.f};
            acc[nt] = __builtin_amdgcn_mfma_f32_16x16x32_bf16(af0, bfr[nt][0], acc[nt], 0, 0, 0);
            acc[nt] = __builtin_amdgcn_mfma_f32_16x16x32_bf16(af1, bfr[nt][1], acc[nt], 0, 0, 0);
        }
        #pragma unroll
        for (int r = 0; r < 4; ++r) {
            int node = m0 + quad * 4 + r;
            if (node >= n) continue;
            float dv = FINAL ? 0.0f : dis[node];
            #pragma unroll
            for (int nt = 0; nt < 4; ++nt) {
                int j = nt * 16 + l15;
                float o = acc[nt][r] + bj[nt];
                if (FINAL) ((float*)outp)[(size_t)node * FDIM + j] = fmaxf(o, 0.0f);
                else ((bf16*)outp)[(size_t)node * FDIM + j] = __float2bfloat16(dv * o);
            }
        }
    }
}

extern "C" void kernel_launch(void* const* d_in, const int* in_sizes, int n_in,
                              void* d_out, int out_size, void* d_ws, size_t ws_size,
                              hipStream_t stream) {
    const float* x    = (const float*)d_in[0];
    const float* feat = (const float*)d_in[1];
    const int*   ei   = (const int*)d_in[2];
    const float* W1   = (const float*)d_in[3];
    const float* b1   = (const float*)d_in[4];
    const float* W2   = (const float*)d_in[5];
    const float* b2   = (const float*)d_in[6];
    const float* Wfc  = (const float*)d_in[7];
    const float* bfc  = (const float*)d_in[8];
    float* out = (float*)d_out;

    const int n = in_sizes[0] / 32;   // 100000
    const int E = in_sizes[2] / 2;    // 1600000 (multiple of 4)
    const int* row = ei;
    const int* col = ei + E;

    const int psize = (((n + NPART - 1) / NPART) + 3) & ~3;   // 25000
    const int psize4 = psize >> 2;                            // 6250
    const int P  = (n + BW - 1) / BW;                         // 196
    const int CH = (((E + NB - 1) / NB) + 3) & ~3;            // 6252 (x4 aligned)
    const int total = P * NB;                                 // 50176
    const int ndis4 = (((n + 3) / 4) + 255) / 256;            // 98

    // ws: off[n+1] | dis[n] | M[total] | bsum[256] | s4[E] | rows4[E]
    //     | (16B-aligned) bufA(bf16 64n) | bufB(bf16 64n)
    // part (NPART*GPB*psize4 u32 = 6.4 MB) aliases bufA (consumed in k_ds1
    // before k_linc writes g1 into bufA).
    int*   off  = (int*)d_ws;
    float* dis  = (float*)(off + (size_t)n + 1);
    int*   M    = (int*)(dis + n);
    int*   bsum = M + (size_t)total;
    int*   s4    = bsum + 256;
    int*   rows4 = s4 + E;
    size_t co = (size_t)(rows4 + E - (int*)d_ws);
    co = (co + 3) & ~(size_t)3;                  // 16B align for v8s loads
    bf16*  bufA  = (bf16*)((int*)d_ws + co);
    bf16*  bufB  = bufA + (size_t)n * FDIM;
    unsigned* part = (unsigned*)bufA;

    k_h2<<<NPART * GPB + NB, 1024, 0, stream>>>(row, col, part, M, E, n,
                                                psize, psize4, P, CH);
    k_ds1<<<ndis4 + P, 256, 0, stream>>>(part, dis, M, bsum, n, psize4, ndis4, P);
    k_csc<<<NB, 1024, 0, stream>>>(row, col, M, bsum, s4, E, CH, P);
    k_fsort<<<P, 1024, 0, stream>>>(s4, bsum, rows4, off, n, E, P);
    k_linc<<<GPLIN, 256, 0, stream>>>(x, feat, W1, b1, dis, bufA, n);
    // layer 2: gather(g1)->a1 ; mat: g2 = bf16(dis*(a1@W2+b2))
    k_gather<<<(n + 3) / 4, 256, 0, stream>>>(rows4, off, dis, bufA, bufB, n);
    k_mat<false><<<512, 256, 0, stream>>>(bufB, W2, b2, dis, bufA, n);
    // fc: gather(g2)->a2 ; out = relu(a2@Wfc+bfc)
    k_gather<<<(n + 3) / 4, 256, 0, stream>>>(rows4, off, dis, bufA, bufB, n);
    k_mat<true><<<512, 256, 0, stream>>>(bufB, Wfc, bfc, dis, out, n);
}